// Round 1
// baseline (72.233 us; speedup 1.0000x reference)
//
#include <hip/hip_runtime.h>

// Closed-form quanvolution:
//   per wire w: z_w = cos(alpha_w)*cos(beta_w)*cos(theta_w) - sin(beta_w)*sin(theta_w)
//   (Rz drops out of Z-expectations; CNOT chain => cumulative products)
//   out = z0*(W0 + z1*(W1 + z2*(W2 + z3*W3)))
// One thread computes 2 adjacent patches: two float4 loads, one float2 store.

__global__ __launch_bounds__(256) void quanv_kernel(
    const float* __restrict__ x,
    const float* __restrict__ params,
    const float* __restrict__ Wm,
    float* __restrict__ out,
    int total)   // total = B * 98  (14 patch-rows * 7 pairs per image)
{
    int t = blockIdx.x * blockDim.x + threadIdx.x;
    if (t >= total) return;

    int b  = t / 98;
    int r  = t - b * 98;
    int i  = r / 7;        // patch row 0..13
    int p2 = r - i * 7;    // pair of patch columns 0..6

    // Wave-uniform gate constants (Rx angle alpha, Ry angle beta per wire).
    float A[4], Bs[4], Wv[4];
#pragma unroll
    for (int w = 0; w < 4; ++w) {
        float alpha = params[3 * w + 0];
        float beta  = params[3 * w + 1];
        A[w]  = __cosf(alpha) * __cosf(beta);
        Bs[w] = __sinf(beta);
        Wv[w] = Wm[w];
    }

    // Patch rows: x[b, 2i, 4*p2 .. 4*p2+3] and x[b, 2i+1, ...]
    const float* base = x + (size_t)b * 784;
    float4 r0 = *(reinterpret_cast<const float4*>(base + (2 * i)     * 28) + p2);
    float4 r1 = *(reinterpret_cast<const float4*>(base + (2 * i + 1) * 28) + p2);

    // Patch 0 thetas (wires 0..3): r0.x, r0.y, r1.x, r1.y
    // Patch 1 thetas:              r0.z, r0.w, r1.z, r1.w
    float th0[4] = {r0.x, r0.y, r1.x, r1.y};
    float th1[4] = {r0.z, r0.w, r1.z, r1.w};

    float res[2];
#pragma unroll
    for (int p = 0; p < 2; ++p) {
        const float* th = (p == 0) ? th0 : th1;
        float z[4];
#pragma unroll
        for (int w = 0; w < 4; ++w) {
            float s, c;
            __sincosf(th[w], &s, &c);
            z[w] = A[w] * c - Bs[w] * s;
        }
        res[p] = z[0] * (Wv[0] + z[1] * (Wv[1] + z[2] * (Wv[2] + z[3] * Wv[3])));
    }

    *reinterpret_cast<float2*>(out + (size_t)b * 196 + i * 14 + 2 * p2) =
        make_float2(res[0], res[1]);
}

extern "C" void kernel_launch(void* const* d_in, const int* in_sizes, int n_in,
                              void* d_out, int out_size, void* d_ws, size_t ws_size,
                              hipStream_t stream) {
    const float* x      = (const float*)d_in[0];
    const float* params = (const float*)d_in[1];
    const float* W      = (const float*)d_in[2];
    float* out          = (float*)d_out;

    int B     = in_sizes[0] / 784;   // (B,1,28,28)
    int total = B * 98;              // 2 patches per thread
    int block = 256;
    int grid  = (total + block - 1) / block;
    quanv_kernel<<<grid, block, 0, stream>>>(x, params, W, out, total);
}

// Round 2
// 70.767 us; speedup vs baseline: 1.0207x; 1.0207x over previous
//
#include <hip/hip_runtime.h>

// Closed-form quanvolution:
//   per wire w: z_w = cos(alpha_w)*cos(beta_w)*cos(theta_w) - sin(beta_w)*sin(theta_w)
//   (Rz drops out of Z-expectations; CNOT chain 0->1->2->3 makes output bits
//    cumulative XORs, so <Z_w> = prod_{k<=w} z_k for a product state)
//   out = z0*(W0 + z1*(W1 + z2*(W2 + z3*W3)))
// One thread computes 2 adjacent patches: two float4 row loads, one float2 store.
// Fully straight-line (no local arrays / runtime-indexed pointers) to guarantee
// register allocation — no scratch.

__global__ __launch_bounds__(256) void quanv_kernel(
    const float* __restrict__ x,
    const float* __restrict__ params,
    const float* __restrict__ Wm,
    float* __restrict__ out,
    int total)   // total = B * 98  (14 patch-rows * 7 float4-pairs per image)
{
    int t = blockIdx.x * blockDim.x + threadIdx.x;
    if (t >= total) return;

    int b  = t / 98;       // image
    int r  = t - b * 98;
    int i  = r / 7;        // patch row 0..13
    int p2 = r - i * 7;    // pair of patch columns 0..6

    // Coalesced, 16B-aligned loads of the two image rows feeding this patch pair.
    const float* base = x + (size_t)b * 784 + 56 * i;   // row 2i start
    float4 r0 = reinterpret_cast<const float4*>(base)[p2];
    float4 r1 = reinterpret_cast<const float4*>(base + 28)[p2];

    // Wave-uniform gate constants (addresses uniform -> scalar loads).
    float ca0 = __cosf(params[0])  * __cosf(params[1]);  float sb0 = __sinf(params[1]);
    float ca1 = __cosf(params[3])  * __cosf(params[4]);  float sb1 = __sinf(params[4]);
    float ca2 = __cosf(params[6])  * __cosf(params[7]);  float sb2 = __sinf(params[7]);
    float ca3 = __cosf(params[9])  * __cosf(params[10]); float sb3 = __sinf(params[10]);
    float w0 = Wm[0], w1 = Wm[1], w2 = Wm[2], w3 = Wm[3];

    float s, c;

    // Patch 0: thetas = r0.x (wire0), r0.y (wire1), r1.x (wire2), r1.y (wire3)
    __sincosf(r0.x, &s, &c); float z0 = ca0 * c - sb0 * s;
    __sincosf(r0.y, &s, &c); float z1 = ca1 * c - sb1 * s;
    __sincosf(r1.x, &s, &c); float z2 = ca2 * c - sb2 * s;
    __sincosf(r1.y, &s, &c); float z3 = ca3 * c - sb3 * s;
    float res0 = z0 * (w0 + z1 * (w1 + z2 * (w2 + z3 * w3)));

    // Patch 1: thetas = r0.z, r0.w, r1.z, r1.w
    __sincosf(r0.z, &s, &c); float y0 = ca0 * c - sb0 * s;
    __sincosf(r0.w, &s, &c); float y1 = ca1 * c - sb1 * s;
    __sincosf(r1.z, &s, &c); float y2 = ca2 * c - sb2 * s;
    __sincosf(r1.w, &s, &c); float y3 = ca3 * c - sb3 * s;
    float res1 = y0 * (w0 + y1 * (w1 + y2 * (w2 + y3 * w3)));

    *reinterpret_cast<float2*>(out + (size_t)b * 196 + i * 14 + 2 * p2) =
        make_float2(res0, res1);
}

extern "C" void kernel_launch(void* const* d_in, const int* in_sizes, int n_in,
                              void* d_out, int out_size, void* d_ws, size_t ws_size,
                              hipStream_t stream) {
    const float* x      = (const float*)d_in[0];
    const float* params = (const float*)d_in[1];
    const float* W      = (const float*)d_in[2];
    float* out          = (float*)d_out;

    int B     = in_sizes[0] / 784;   // (B,1,28,28)
    int total = B * 98;              // 2 patches per thread
    int block = 256;
    int grid  = (total + block - 1) / block;
    quanv_kernel<<<grid, block, 0, stream>>>(x, params, W, out, total);
}